// Round 15
// baseline (490.091 us; speedup 1.0000x reference)
//
#include <hip/hip_runtime.h>
#include <math.h>

#define CK_A (-0.75f)

typedef __attribute__((ext_vector_type(8))) short bf16x8;
typedef __attribute__((ext_vector_type(4))) float f32x4;

struct CImg { const void* in; void* out; int H, W, tiles; long inBS, outBS, sStride; };

__device__ __forceinline__ float cubicw(float t){
  float at = fabsf(t);
  float at2 = at*at, at3 = at2*at;
  if (at <= 1.f) return (CK_A+2.f)*at3 - (CK_A+3.f)*at2 + 1.f;
  if (at < 2.f)  return CK_A*at3 - 5.f*CK_A*at2 + 8.f*CK_A*at - 4.f*CK_A;
  return 0.f;
}

__device__ __forceinline__ unsigned short f2bf_rne(float f){
  unsigned int u = __float_as_uint(f);
  unsigned int r = (u + 0x7fffu + ((u>>16)&1u)) >> 16;
  return (unsigned short)r;
}
__device__ __forceinline__ float bf2f(unsigned short h){
  return __uint_as_float(((unsigned int)h)<<16);
}
__device__ __forceinline__ unsigned pack_bf(float v){
  unsigned short h = f2bf_rne(v);
  unsigned short l = f2bf_rne(v - bf2f(h));
  return ((unsigned)h<<16) | (unsigned)l;
}
__device__ __forceinline__ float unpack_bf(unsigned p){
  return bf2f((unsigned short)(p>>16)) + bf2f((unsigned short)(p&0xffffu));
}

__device__ __forceinline__ void merge_ms(float& m, float& s, float m2, float s2){
  float M = fmaxf(m, m2);
  s = s*__expf(m - M) + s2*__expf(m2 - M);
  m = M;
}

#define MFB(a,b,c) __builtin_amdgcn_mfma_f32_16x16x32_bf16(a,b,c,0,0,0)

typedef const __attribute__((address_space(1))) unsigned int* gp1_t;
typedef __attribute__((address_space(3))) unsigned int* lp3_t;
__device__ __forceinline__ void dma16(const void* g, void* l){
  __builtin_amdgcn_global_load_lds((gp1_t)g, (lp3_t)l, 16, 0, 0);
}

// ---------------- conv0: fp32 feat + packed aux + channel-sum atomics -----
__global__ __launch_bounds__(256) void conv0_d(CImg A, CImg B,
    const float* __restrict__ w, const float* __restrict__ bias,
    unsigned* __restrict__ pOutA, unsigned* __restrict__ pOutB,
    float* __restrict__ meanb){
  bool isA = (int)blockIdx.x < A.tiles;
  const float* in = (const float*)(isA ? A.in : B.in);
  float* out = (float*)(isA ? A.out : B.out);
  unsigned* pout = isA ? pOutA : pOutB;
  int H = isA ? A.H : B.H, W = isA ? A.W : B.W;
  long inBS = isA ? A.inBS : B.inBS, outBS = isA ? A.outBS : B.outBS;
  int tile = isA ? blockIdx.x : blockIdx.x - A.tiles;
  int tilesX = (W + 15) >> 4;
  int tx0 = (tile % tilesX) << 4, ty0 = (tile / tilesX) << 4;
  int cob = blockIdx.y * 4;
  int b = blockIdx.z;
  int lx = threadIdx.x & 15, ly = threadIdx.x >> 4;
  __shared__ float tile_s[3][18][20];
  __shared__ float credu[4][4];
  float acc[4] = {0.f,0.f,0.f,0.f};
  const float* inb = in + (long)b*inBS;
  int ox = tx0+lx, oy = ty0+ly;
  int HW = H*W;

  for (int idx = threadIdx.x; idx < 3*324; idx += 256){
    int cl = idx/324, rem = idx - cl*324;
    int r = rem/18, c = rem - r*18;
    int gy = ty0 + r - 1, gx = tx0 + c - 1;
    const float* ic = inb + (long)cl*HW;
    tile_s[cl][r][c] = (gy>=0 && gy<H && gx>=0 && gx<W) ? ic[(long)gy*W+gx] : 0.f;
  }
  __syncthreads();
  #pragma unroll
  for (int cl=0; cl<3; cl++){
    float t00=tile_s[cl][ly+0][lx+0], t01=tile_s[cl][ly+0][lx+1], t02=tile_s[cl][ly+0][lx+2];
    float t10=tile_s[cl][ly+1][lx+0], t11=tile_s[cl][ly+1][lx+1], t12=tile_s[cl][ly+1][lx+2];
    float t20=tile_s[cl][ly+2][lx+0], t21=tile_s[cl][ly+2][lx+1], t22=tile_s[cl][ly+2][lx+2];
    #pragma unroll
    for (int j=0;j<4;j++){
      const float* wp = w + ((long)(cob+j)*3 + cl)*9;
      float a = acc[j];
      a = fmaf(t00, wp[0], a); a = fmaf(t01, wp[1], a); a = fmaf(t02, wp[2], a);
      a = fmaf(t10, wp[3], a); a = fmaf(t11, wp[4], a); a = fmaf(t12, wp[5], a);
      a = fmaf(t20, wp[6], a); a = fmaf(t21, wp[7], a); a = fmaf(t22, wp[8], a);
      acc[j] = a;
    }
  }
  int lane = threadIdx.x & 63, wv = threadIdx.x >> 6;
  // conv0 tiles are always full (96,48 divisible by 16)
  #pragma unroll
  for (int j=0;j<4;j++){
    float v = fmaxf(acc[j] + bias[cob+j], 0.f);
    long pix = (long)(cob+j)*HW + (long)oy*W + ox;
    out[(long)b*outBS + pix] = v;
    pout[(long)b*64*HW + pix] = pack_bf(v);
    acc[j] = v;
  }
  // per-channel block sums -> atomic mean accumulation
  #pragma unroll
  for (int j=0;j<4;j++){
    float s = acc[j];
    #pragma unroll
    for (int o=1;o<64;o<<=1) s += __shfl_xor(s, o);
    if (lane==0) credu[j][wv] = s;
  }
  __syncthreads();
  if (threadIdx.x < 4){
    int j = threadIdx.x;
    float s = credu[j][0]+credu[j][1]+credu[j][2]+credu[j][3];
    atomicAdd(&meanb[b*320 + cob + j], s);
  }
}

// ---------------- weight pre-pack, all layers one launch ----------------
__global__ void prep_w_all(const float* __restrict__ w1, const float* __restrict__ w2,
                           const float* __restrict__ w3, const float* __restrict__ w4,
                           const float* __restrict__ w5, const float* __restrict__ w6,
                           const float* __restrict__ w7, unsigned short* __restrict__ wp){
  const int ciT[7] = {64,64,128,128,256,256,256};
  const int coT[7] = {64,128,128,256,256,256,256};
  int l = blockIdx.y;
  const float* w = l==0?w1: l==1?w2: l==2?w3: l==3?w4: l==4?w5: l==5?w6: w7;
  long offv = 0;
  for (int i=0;i<7;i++){ if (i<l) offv += 9L*ciT[i]*coT[i]*2; }
  long total = 9L*ciT[l]*coT[l]*2;
  long e = (long)blockIdx.x*256 + threadIdx.x;
  if (e >= total) return;
  int CI = ciT[l], CO = coT[l];
  int j = (int)(e & 7);
  int lane = (int)((e>>3) & 63);
  int h = (int)((e>>9) & 1);
  long rem = e >> 10;
  int G = CO >> 4, KC = CI >> 5;
  int g = (int)(rem % G); long q = rem / G;
  int kc = (int)(q % KC); int o = (int)(q / KC);
  int co = (g<<4) + (lane & 15);
  int ci = (kc<<5) + ((lane>>4)<<3) + j;
  float v = w[((long)co*CI + ci)*9 + o];
  unsigned short hi = f2bf_rne(v);
  wp[offv + e] = (h==0) ? hi : f2bf_rne(v - bf2f(hi));
}

// ---------------- implicit-GEMM MFMA conv, packed in, optional fused pool -
union AB { bf16x8 v; uint4 u; };

__global__ __launch_bounds__(256) void conv_mfma_d(
    CImg A, CImg B, const unsigned short* __restrict__ Wp,
    const float* __restrict__ bias, int CI, int CO, int nci, int S,
    unsigned* __restrict__ poolA, unsigned* __restrict__ poolB, long poolBSa, long poolBSb)
{
  bool isA = (int)blockIdx.x < A.tiles;
  const unsigned* in = (const unsigned*)(isA ? A.in : B.in);
  void* outv = isA ? A.out : B.out;
  unsigned* poolOut = isA ? poolA : poolB;
  long poolBS = isA ? poolBSa : poolBSb;
  int H = isA ? A.H : B.H, W = isA ? A.W : B.W;
  long inBS = isA ? A.inBS : B.inBS, outBS = isA ? A.outBS : B.outBS;
  long sStride = isA ? A.sStride : B.sStride;
  int tile = isA ? blockIdx.x : blockIdx.x - A.tiles;

  int HW = H*W;
  int tilesX = (W+7)>>3;
  int tx0 = (tile % tilesX)<<3, ty0 = (tile / tilesX)<<3;
  int cobase = blockIdx.y << 6;
  int s = blockIdx.z % S, b = blockIdx.z / S;
  int tid = threadIdx.x, lane = tid & 63, wid = tid>>6;
  int wm = wid>>1, wn = wid&1;
  int KC = CI>>5, G = CO>>4;
  __shared__ __align__(16) char smem[16928];
  unsigned short* Bth = (unsigned short*)smem;
  unsigned short* Btl = Bth + 4000;
  const unsigned* inb = in + (long)b*inBS;

  int sofs[13]; int sla[13];
  #pragma unroll
  for (int i=0;i<13;i++){
    int e = tid + i*256;
    int cidx = e / 100, pix = e - cidx*100;
    int hy = pix/10, hx = pix - hy*10;
    int gy = ty0 - 1 + hy, gx = tx0 - 1 + hx;
    bool v = (gy>=0) && (gy<H) && (gx>=0) && (gx<W);
    sofs[i] = v ? (cidx*HW + gy*W + gx) : -1;
    sla[i] = pix*40 + cidx;
  }

  int n15 = lane & 15;
  int klane8 = (lane>>4)<<3;
  int p0 = wn*32 + n15;
  int base0 = ((p0>>3)*10 + (p0&7))*40 + klane8;
  int p1 = p0 + 16;
  int base1 = ((p1>>3)*10 + (p1&7))*40 + klane8;
  int g0 = (cobase>>4) + wm*2;

  f32x4 acc[2][2];
  #pragma unroll
  for (int i=0;i<2;i++)
    #pragma unroll
    for (int j=0;j<2;j++) acc[i][j] = (f32x4){0.f,0.f,0.f,0.f};

  int nkc = nci >> 5;
  for (int kk=0; kk<nkc; kk++){
    int ci0 = s*nci + (kk<<5);
    __syncthreads();
    #pragma unroll
    for (int i=0;i<12;i++){
      unsigned p = (sofs[i] >= 0) ? inb[(long)ci0*HW + sofs[i]] : 0u;
      Bth[sla[i]] = (unsigned short)(p>>16);
      Btl[sla[i]] = (unsigned short)(p & 0xffffu);
    }
    if (tid < 128){
      unsigned p = (sofs[12] >= 0) ? inb[(long)ci0*HW + sofs[12]] : 0u;
      Bth[sla[12]] = (unsigned short)(p>>16);
      Btl[sla[12]] = (unsigned short)(p & 0xffffu);
    }
    __syncthreads();
    int kc = ci0 >> 5;
    const unsigned short* wpb = Wp + (long)kc*G*1024 + (long)lane*8;
    #pragma unroll
    for (int o=0;o<9;o++){
      const int dy = o/3, dx = o - dy*3;
      const int sh = (dy*10+dx)*40;
      const unsigned short* wo = wpb + (long)o*KC*G*1024;
      AB a0h,a0l,a1h,a1l, b0h,b0l,b1h,b1l;
      a0h.u = *(const uint4*)(wo + (long)g0*1024);
      a0l.u = *(const uint4*)(wo + (long)g0*1024 + 512);
      a1h.u = *(const uint4*)(wo + (long)(g0+1)*1024);
      a1l.u = *(const uint4*)(wo + (long)(g0+1)*1024 + 512);
      b0h.v = *(const bf16x8*)&Bth[base0 + sh];
      b0l.v = *(const bf16x8*)&Btl[base0 + sh];
      b1h.v = *(const bf16x8*)&Bth[base1 + sh];
      b1l.v = *(const bf16x8*)&Btl[base1 + sh];
      acc[0][0] = MFB(a0h.v, b0l.v, acc[0][0]);
      acc[0][0] = MFB(a0l.v, b0h.v, acc[0][0]);
      acc[0][0] = MFB(a0h.v, b0h.v, acc[0][0]);
      acc[0][1] = MFB(a0h.v, b1l.v, acc[0][1]);
      acc[0][1] = MFB(a0l.v, b1h.v, acc[0][1]);
      acc[0][1] = MFB(a0h.v, b1h.v, acc[0][1]);
      acc[1][0] = MFB(a1h.v, b0l.v, acc[1][0]);
      acc[1][0] = MFB(a1l.v, b0h.v, acc[1][0]);
      acc[1][0] = MFB(a1h.v, b0h.v, acc[1][0]);
      acc[1][1] = MFB(a1h.v, b1l.v, acc[1][1]);
      acc[1][1] = MFB(a1l.v, b1h.v, acc[1][1]);
      acc[1][1] = MFB(a1h.v, b1h.v, acc[1][1]);
    }
  }

  if (poolOut){
    // L1 path: relu(acc+bias) -> LDS tile -> 2x2 maxpool -> packed pooled out
    float* pbuf = (float*)smem;          // [64 co][66]
    __syncthreads();
    #pragma unroll
    for (int ng=0; ng<2; ng++){
      int p = wn*32 + ng*16 + n15;
      #pragma unroll
      for (int mg=0; mg<2; mg++){
        #pragma unroll
        for (int r=0;r<4;r++){
          int col = wm*32 + mg*16 + ((lane>>4)<<2) + r;   // co local
          float v = fmaxf(acc[mg][ng][r] + bias[cobase + col], 0.f);
          pbuf[col*66 + p] = v;
        }
      }
    }
    __syncthreads();
    int Wp2 = W>>1, HWp = (H>>1)*Wp2;
    unsigned* outp = poolOut + (long)b*poolBS;
    #pragma unroll
    for (int t=0;t<4;t++){
      int o = tid*4 + t;           // 0..1023 = 64co x 16 pooled px
      int col = o >> 4, pp = o & 15;
      int py = pp >> 2, px2 = pp & 3;
      int pbase = col*66 + py*16 + px2*2;
      float v0 = pbuf[pbase], v1 = pbuf[pbase+1];
      float v2 = pbuf[pbase+8], v3 = pbuf[pbase+9];
      float mx = fmaxf(fmaxf(v0,v1), fmaxf(v2,v3));
      outp[(long)(cobase+col)*HWp + (long)((ty0>>1)+py)*Wp2 + (tx0>>1)+px2] = pack_bf(mx);
    }
    return;
  }

  #pragma unroll
  for (int ng=0; ng<2; ng++){
    int p = wn*32 + ng*16 + n15;
    int gy = ty0 + (p>>3), gx = tx0 + (p&7);
    bool ok = (gy<H) && (gx<W);
    #pragma unroll
    for (int mg=0; mg<2; mg++){
      #pragma unroll
      for (int r=0;r<4;r++){
        if (ok){
          int co = cobase + wm*32 + mg*16 + ((lane>>4)<<2) + r;
          long idx = (long)co*HW + (long)gy*W + gx;
          float v = acc[mg][ng][r];
          if (bias){
            unsigned* outp = (unsigned*)outv + (long)b*outBS;
            outp[idx] = pack_bf(fmaxf(v + bias[co], 0.f));
          } else {
            float* outp = (float*)outv + (long)s*sStride + (long)b*outBS;
            outp[idx] = v;
          }
        }
      }
    }
  }
}

// ---------------- partial reduce + bias + relu -> packed out -------------
__global__ void reduce_d(const float* __restrict__ pA, const float* __restrict__ pB,
                         const float* __restrict__ bias,
                         unsigned* __restrict__ oA, unsigned* __restrict__ oB,
                         int S, long sStrA, long sStrB, int CO, int HWa, int HWb,
                         long oBSa, long oBSb){
  int img = blockIdx.y;
  const float* part = img ? pB : pA;
  unsigned* out = img ? oB : oA;
  int HW = img ? HWb : HWa;
  long sStride = img ? sStrB : sStrA;
  long outBS = img ? oBSb : oBSa;
  long tot = 2L*CO*HW;
  long e = (long)blockIdx.x*256 + threadIdx.x;
  if (e >= tot) return;
  long b = e / ((long)CO*HW);
  long r = e - b*(long)CO*HW;
  float v = 0.f;
  for (int s=0;s<S;s++) v += part[(long)s*sStride + e];
  int co = (int)(r / HW);
  out[b*outBS + r] = pack_bf(fmaxf(v + bias[co], 0.f));
}

// ---------------- fused reduce + bias + relu + 2x2 maxpool (pool2) -------
__global__ void reduce_pool_d(const float* __restrict__ pA, const float* __restrict__ pB,
                              const float* __restrict__ bias,
                              unsigned* __restrict__ oA, unsigned* __restrict__ oB,
                              int S, long sStrA, long sStrB, int CO, int Ha, int Wa,
                              int Hb, int Wb){
  int img = blockIdx.y;
  const float* part = img ? pB : pA;
  unsigned* out = img ? oB : oA;
  int H = img ? Hb : Ha, W = img ? Wb : Wa;
  long sStride = img ? sStrB : sStrA;
  int Hp = H>>1, Wp = W>>1;
  long tot = 2L*CO*Hp*Wp;
  long e = (long)blockIdx.x*256 + threadIdx.x;
  if (e >= tot) return;
  int x = (int)(e % Wp); long t = e / Wp;
  int y = (int)(t % Hp); t /= Hp;
  int ch = (int)(t % CO); long b = t / CO;
  float bI = bias[ch];
  long base = b*(long)CO*H*W + (long)ch*H*W + (long)(2*y)*W + 2*x;
  long po[4] = {base, base+1, base+W, base+W+1};
  float mx = -INFINITY;
  #pragma unroll
  for (int k=0;k<4;k++){
    float a = bI;
    for (int s=0;s<S;s++) a += part[(long)s*sStride + po[k]];
    mx = fmaxf(mx, fmaxf(a, 0.f));
  }
  out[e] = pack_bf(mx);
}

// ---------------- bicubic upsample from packed, fp32 out + mean atomics --
__global__ __launch_bounds__(256) void bicubic_d(
    const unsigned* __restrict__ inA, float* __restrict__ outA,
    const unsigned* __restrict__ inB, float* __restrict__ outB,
    float* __restrict__ meanb){
  int c = blockIdx.x;
  int img = blockIdx.y >> 1, b = blockIdx.y & 1;
  const unsigned* in = img ? inB : inA;
  float* out = img ? outB : outA;
  int Hin = img ? 12 : 24, Win = Hin, Hout = img ? 48 : 96, Wout = Hout;
  long inBS = img ? 256L*144 : 256L*576;
  long outBS = img ? 320L*2304 : 320L*9216;
  __shared__ float s[576];
  __shared__ float sred[4];
  const unsigned* ip = in + (long)b*inBS + (long)c*Hin*Win;
  float* op = out + (long)b*outBS + (long)c*Hout*Wout;
  int n = Hin*Win;
  for (int i = threadIdx.x; i < n; i += 256) s[i] = unpack_bf(ip[i]);
  __syncthreads();
  float scy = (float)((double)(Hin-1)/(double)(Hout-1));
  float scx = scy;
  int total = Hout*Wout;
  float lsum = 0.f;
  for (int idx = threadIdx.x; idx < total; idx += 256){
    int ox = idx % Wout, oy = idx / Wout;
    float py = oy * scy, px = ox * scx;
    float iy0f = floorf(py), ix0f = floorf(px);
    int iy0 = (int)iy0f, ix0 = (int)ix0f;
    float fy = py - iy0f, fx = px - ix0f;
    float wy[4], wx[4]; int xs[4], ys[4];
    #pragma unroll
    for (int t=0;t<4;t++){
      wy[t] = cubicw(fy - (float)(t-1));
      wx[t] = cubicw(fx - (float)(t-1));
      ys[t] = min(max(iy0 + t - 1, 0), Hin-1);
      xs[t] = min(max(ix0 + t - 1, 0), Win-1);
    }
    float acc = 0.f;
    #pragma unroll
    for (int i=0;i<4;i++){
      const float* row = &s[ys[i]*Win];
      float rs = wx[0]*row[xs[0]] + wx[1]*row[xs[1]] + wx[2]*row[xs[2]] + wx[3]*row[xs[3]];
      acc = fmaf(wy[i], rs, acc);
    }
    op[idx] = acc;
    lsum += acc;
  }
  int lane = threadIdx.x & 63, wv = threadIdx.x >> 6;
  #pragma unroll
  for (int o=1;o<64;o<<=1) lsum += __shfl_xor(lsum, o);
  if (lane==0) sred[wv] = lsum;
  __syncthreads();
  if (threadIdx.x==0)
    atomicAdd(&meanb[b*320 + 64 + c], sred[0]+sred[1]+sred[2]+sred[3]);
}

// ---------------- normalize + split + transpose (both feats) -------------
__global__ __launch_bounds__(256) void split_bf16_d(const float* __restrict__ fR, const float* __restrict__ fT,
    const float* __restrict__ mean,
    unsigned short* __restrict__ AhR, unsigned short* __restrict__ AlR,
    unsigned short* __restrict__ BhT, unsigned short* __restrict__ BlT){
  bool isR = blockIdx.x < 288;
  const float* feat = isR ? fR : fT;
  unsigned short* oh = isR ? AhR : BhT;
  unsigned short* ol = isR ? AlR : BlT;
  int P = isR ? 9216 : 2304;
  int m0 = (isR ? blockIdx.x : blockIdx.x - 288) * 32;
  int b = blockIdx.y;
  __shared__ unsigned int t[32][321];
  int ml = threadIdx.x & 31, kq = threadIdx.x >> 5;
  const float* fp = feat + (long)b*320*P + m0 + ml;
  for (int k = kq*40; k < kq*40+40; k++){
    float mu = mean[b*320+k] * (1.f/11520.f);
    float v = (fp[(long)k*P] - mu) / (mu + 1e-8f);
    t[ml][k] = pack_bf(v);
  }
  __syncthreads();
  long base = ((long)b*P + m0)*320;
  for (int idx = threadIdx.x; idx < 32*320; idx += 256){
    int m = idx/320, k = idx - m*320;
    unsigned int p = t[m][k];
    oh[base + (long)m*320 + k] = (unsigned short)(p>>16);
    ol[base + (long)m*320 + k] = (unsigned short)(p & 0xffffu);
  }
}

// ---------------- split-bf16 MFMA dist GEMM + fused column stats --------
__global__ __launch_bounds__(256) void gemm_mfma(
    const unsigned short* __restrict__ Ah, const unsigned short* __restrict__ Al,
    const unsigned short* __restrict__ Bh, const unsigned short* __restrict__ Bl,
    float* __restrict__ D, const float* __restrict__ coefr,
    float* __restrict__ pm, float* __restrict__ ps){
  const int N = 2304, K = 320;
  int flat = (int)blockIdx.y * 18 + (int)blockIdx.x;   // nwg = 1296, %8==0
  int nf = (flat & 7) * 162 + (flat >> 3);
  int mb = nf / 18, nb = nf - mb*18;
  int n0 = nb*128, m0 = mb*128;
  __shared__ __align__(16) unsigned short SF[16384];   // 32 KB
  int tid = threadIdx.x, lane = tid & 63, wid = tid >> 6;
  int wm = wid >> 1, wn = wid & 1;
  int n15 = lane & 15, q = lane >> 4;
  f32x4 acc[4][4];
  #pragma unroll
  for (int i=0;i<4;i++)
    #pragma unroll
    for (int j=0;j<4;j++) acc[i][j] = (f32x4){0.f,0.f,0.f,0.f};

  const unsigned short* srcB[8];
  #pragma unroll
  for (int i=0;i<8;i++){
    int li = i*256 + tid;
    int rem = li & 1023;
    int row = rem >> 3, sg = rem & 7;
    int seg = sg ^ (row & 7);
    if (li < 1024) srcB[i] = ((seg<4) ? Ah : Al) + (long)(m0+row)*K + (seg&3)*8;
    else           srcB[i] = ((seg<4) ? Bh : Bl) + (long)(n0+row)*K + (seg&3)*8;
  }

  int aH[4], aL[4], bH[4], bL[4];
  #pragma unroll
  for (int g=0; g<4; g++){
    int ra = wm*64 + g*16 + n15;
    int rb = wn*64 + g*16 + n15;
    aH[g] = ra*64 + (( q   ) ^ (ra&7))*8;
    aL[g] = ra*64 + ((q+4) ^ (ra&7))*8;
    bH[g] = 8192 + rb*64 + (( q   ) ^ (rb&7))*8;
    bL[g] = 8192 + rb*64 + ((q+4) ^ (rb&7))*8;
  }

  for (int k0=0; k0<K; k0+=32){
    __syncthreads();
    #pragma unroll
    for (int i=0;i<8;i++){
      dma16(srcB[i] + k0, (void*)&SF[((i<<8) + (wid<<6))<<3]);
    }
    __syncthreads();

    AB af[2][4], bf[2][4];
    #pragma unroll
    for (int g=0; g<4; g++){
      af[0][g].v = *(const bf16x8*)&SF[aH[g]];
      af[1][g].v = *(const bf16x8*)&SF[aL[g]];
      bf[0][g].v = *(const bf16x8*)&SF[bH[g]];
      bf[1][g].v = *(const bf16x8*)&SF[bL[g]];
    }
    #pragma unroll
    for (int mg=0; mg<4; mg++)
      #pragma unroll
      for (int ng=0; ng<4; ng++){
        acc[mg][ng] = MFB(af[0][mg].v, bf[1][ng].v, acc[mg][ng]);
        acc[mg][ng] = MFB(af[1][mg].v, bf[0][ng].v, acc[mg][ng]);
        acc[mg][ng] = MFB(af[0][mg].v, bf[0][ng].v, acc[mg][ng]);
      }
  }
  __syncthreads();

  #pragma unroll
  for (int mg=0; mg<4; mg++)
    #pragma unroll
    for (int ng=0; ng<4; ng++){
      int col = n0 + wn*64 + ng*16 + n15;
      #pragma unroll
      for (int r=0;r<4;r++){
        int rowv = m0 + wm*64 + mg*16 + q*4 + r;
        __builtin_nontemporal_store(acc[mg][ng][r], &D[(long)rowv*N + col]);
      }
    }

  float cr = *coefr;
  float* red = (float*)&SF[0];
  float pmv[4], psv[4];
  #pragma unroll
  for (int ng=0; ng<4; ng++){
    float m = -INFINITY;
    #pragma unroll
    for (int mg=0; mg<4; mg++)
      #pragma unroll
      for (int r=0;r<4;r++) m = fmaxf(m, cr*acc[mg][ng][r]);
    float s = 0.f;
    #pragma unroll
    for (int mg=0; mg<4; mg++)
      #pragma unroll
      for (int r=0;r<4;r++) s += __expf(cr*acc[mg][ng][r] - m);
    #pragma unroll
    for (int o=16;o<64;o<<=1){
      float m2 = __shfl_xor(m,o), s2 = __shfl_xor(s,o);
      merge_ms(m,s,m2,s2);
    }
    pmv[ng]=m; psv[ng]=s;
  }
  if (q==0){
    #pragma unroll
    for (int ng=0; ng<4; ng++){
      int cl = wn*64 + ng*16 + lane;
      red[wm*128 + cl] = pmv[ng];
      red[256 + wm*128 + cl] = psv[ng];
    }
  }
  __syncthreads();
  if (wm==0 && q==0){
    #pragma unroll
    for (int ng=0; ng<4; ng++){
      int cl = wn*64 + ng*16 + lane;
      float m = pmv[ng], s = psv[ng];
      merge_ms(m, s, red[128+cl], red[384+cl]);
      pm[(long)mb*2304 + n0 + cl] = m;
      ps[(long)mb*2304 + n0 + cl] = s;
    }
  }
}

// merge 72 partials, emit q[n] = 0.5*cmax + 0.5*log(csum)
__global__ void colstat_merge(const float* __restrict__ pm, const float* __restrict__ ps,
                              float* __restrict__ qcol){
  int idx = blockIdx.x*256 + threadIdx.x;
  if (idx >= 2304) return;
  float m=-INFINITY, s=0.f;
  for (int k=0;k<72;k++) merge_ms(m, s, pm[(long)k*2304+idx], ps[(long)k*2304+idx]);
  qcol[idx] = 0.5f*m + 0.5f*__logf(s);
}

// ---------------- fused row-stats + confidence + top-10 mean -------------
__global__ __launch_bounds__(256) void conf_topk_f(const float* __restrict__ D,
    const float* __restrict__ coefr, const float* __restrict__ coeft,
    const float* __restrict__ qcol, float* __restrict__ outp){
  int m = blockIdx.x;
  const float* drow = D + (long)m*2304;
  int tid = threadIdx.x, lane = tid & 63, wv = tid >> 6;
  float ct = *coeft, cr = *coefr;
  float v[9], tv[9];
  #pragma unroll
  for (int i=0;i<9;i++){ v[i] = __builtin_nontemporal_load(&drow[tid + i*256]); tv[i] = ct * v[i]; }

  __shared__ float sred[8];
  __shared__ unsigned int cand[40];

  float mx = tv[0];
  #pragma unroll
  for (int i=1;i<9;i++) mx = fmaxf(mx, tv[i]);
  #pragma unroll
  for (int o=1;o<64;o<<=1) mx = fmaxf(mx, __shfl_xor(mx, o));
  if (lane==0) sred[wv] = mx;
  __syncthreads();
  mx = fmaxf(fmaxf(sred[0],sred[1]), fmaxf(sred[2],sred[3]));
  float s = 0.f;
  #pragma unroll
  for (int i=0;i<9;i++) s += __expf(tv[i]-mx);
  #pragma unroll
  for (int o=1;o<64;o<<=1) s += __shfl_xor(s, o);
  if (lane==0) sred[4+wv] = s;
  __syncthreads();
  float rs = sred[4]+sred[5]+sred[6]+sred[7];
  float rho = 0.5f*mx + 0.5f*__logf(rs);
  float hc = 0.5f*(cr+ct);

  unsigned int key[9];
  #pragma unroll
  for (int i=0;i<9;i++){
    int n = i*256 + tid;
    float t = fmaf(hc, v[i], -qcol[n]);
    unsigned int b = __float_as_uint(t);
    b ^= (b >> 31) ? 0xFFFFFFFFu : 0x80000000u;
    key[i] = (b & 0xFFFFF000u) | (unsigned)n;
  }

  for (int t10=0; t10<10; t10++){
    unsigned int lb = key[0];
    #pragma unroll
    for (int i=1;i<9;i++) lb = lb > key[i] ? lb : key[i];
    unsigned int wb = lb;
    #pragma unroll
    for (int o=1;o<64;o<<=1){
      unsigned int x = (unsigned int)__shfl_xor((int)wb, o);
      wb = wb > x ? wb : x;
    }
    if (lane==0) cand[wv*10 + t10] = wb;
    #pragma unroll
    for (int i=0;i<9;i++) if (key[i]==wb) key[i]=0;
  }
  __syncthreads();

  if (wv == 0){
    unsigned int k = (lane < 40) ? cand[lane] : 0u;
    int sel = -1;
    for (int t10=0; t10<10; t10++){
      unsigned int wb = k;
      #pragma unroll
      for (int o=1;o<64;o<<=1){
        unsigned int x = (unsigned int)__shfl_xor((int)wb, o);
        wb = wb > x ? wb : x;
      }
      if (k == wb) k = 0;
      if (lane == t10) sel = (int)(wb & 0xFFFu);
    }
    float c = 0.f;
    if (sel >= 0){
      float t = fmaf(hc, drow[sel], -qcol[sel]);
      c = __expf(t - rho);
    }
    #pragma unroll
    for (int o=1;o<64;o<<=1) c += __shfl_xor(c, o);
    if (lane == 0) outp[m] = c * 0.1f;
  }
}

// ---------------- host ----------------
extern "C" void kernel_launch(void* const* d_in, const int* in_sizes, int n_in,
                              void* d_out, int out_size, void* d_ws, size_t ws_size,
                              hipStream_t stream) {
  const float *W[8], *Bp[8], *xr, *xt, *cr, *ct;
  if (in_sizes[0] == 1728){
    for (int i=0;i<8;i++){ W[i]=(const float*)d_in[2*i]; Bp[i]=(const float*)d_in[2*i+1]; }
    xr=(const float*)d_in[16]; xt=(const float*)d_in[17];
    cr=(const float*)d_in[18]; ct=(const float*)d_in[19];
  } else {
    xr=(const float*)d_in[0]; xt=(const float*)d_in[1];
    cr=(const float*)d_in[2]; ct=(const float*)d_in[3];
    for (int i=0;i<8;i++){ W[i]=(const float*)d_in[4+2*i]; Bp[i]=(const float*)d_in[5+2*i]; }
  }

  const int convCI[8] = {3,64,64,128,128,256,256,256};
  const int convCO[8] = {64,64,128,128,256,256,256,256};
  long wpoff[8]; long wtot = 0;
  for (int l=1;l<8;l++){ wpoff[l] = wtot; wtot += 9L*convCI[l]*convCO[l]*2; }

  float* ws = (float*)d_ws;
  long off = 0;
  auto alloc = [&](long nfl){ float* p = ws + off; off += (nfl + 63) & ~63L; return p; };
  float* featR = alloc(2L*320*9216);
  float* featT = alloc(2L*320*2304);
  float* meanb = alloc(640);
  float* pm    = alloc(72L*2304);
  float* ps    = alloc(72L*2304);
  float* qcol  = alloc(2304);
  unsigned short* wp = (unsigned short*)alloc((wtot+1)/2);
  float* scratch = alloc(9216L*2304);
  if ((size_t)(off*4) > ws_size) return;

  unsigned short* AhR = (unsigned short*)alloc((2L*9216*320 + 1)/2);
  unsigned short* AlR = (unsigned short*)alloc((2L*9216*320 + 1)/2);
  unsigned short* BhT = (unsigned short*)alloc((2L*2304*320 + 1)/2);
  unsigned short* BlT = (unsigned short*)alloc((2L*2304*320 + 1)/2);
  if ((size_t)(off*4) > ws_size) return;

  // conv temporaries (packed u32) inside the dist region
  unsigned* pc0R = (unsigned*)scratch;        // [2,64,96,96] conv0 packed
  unsigned* pc0T = pc0R + 1179648;            // [2,64,48,48]
  unsigned* rB   = pc0T + 294912;             // [2,64,48,48] pool1 R (fused from L1)
  unsigned* b2   = rB + 294912;               // [2,64,24,24] pool1 T
  unsigned* rC   = b2 + 73728;                // [2,128,48,48]
  unsigned* c2   = rC + 589824;               // [2,128,24,24]
  unsigned* rE   = c2 + 147456;               // [2,128,24,24] pool2 R (fused)
  unsigned* e2   = rE + 147456;               // [2,128,12,12] pool2 T
  unsigned* rF   = e2 + 36864;                // [2,256,24,24]
  unsigned* rG   = rF + 294912;               // [2,256,24,24]
  unsigned* f2   = rG + 294912;               // [2,256,12,12]
  unsigned* g2   = f2 + 73728;                // [2,256,12,12]
  float* tPR = (float*)(g2 + 73728);          // R partials fp32
  float* tPT = tPR + 1179648;                 // T partials fp32
  float* dist = scratch;

  auto mkimg = [](const void* in, void* out, int H, int Wd, int tiles,
                  long inBS, long outBS, long sStr){
    CImg c; c.in=in; c.out=out; c.H=H; c.W=Wd; c.tiles=tiles;
    c.inBS=inBS; c.outBS=outBS; c.sStride=sStr; return c;
  };

  hipMemsetAsync(meanb, 0, 640*sizeof(float), stream);
  prep_w_all<<<dim3(4608,7), 256, 0, stream>>>(W[1],W[2],W[3],W[4],W[5],W[6],W[7], wp);

  // conv0 (both images): fp32 feat + packed aux + mean atomics
  {
    CImg A = mkimg(xr, featR, 96,96, 36, 3L*9216, 320L*9216, 0);
    CImg B = mkimg(xt, featT, 48,48, 9, 3L*2304, 320L*2304, 0);
    conv0_d<<<dim3(45,16,2), 256, 0, stream>>>(A, B, W[0], Bp[0], pc0R, pc0T, meanb);
  }
  // L1 (S=1, packed in) with fused 2x2 maxpool -> rB/b2 directly
  {
    CImg A = mkimg(pc0R, nullptr, 96,96, 144, 64L*9216, 0, 0);
    CImg B = mkimg(pc0T, nullptr, 48,48, 36, 64L*2304, 0, 0);
    conv_mfma_d<<<dim3(180,1,2), 256, 0, stream>>>(A,B, wp+wpoff[1], Bp[1], 64,64,64,1,
                                                   rB, b2, 64L*2304, 64L*576);
  }
  // L2 (S=2)
  {
    CImg A = mkimg(rB, tPR, 48,48, 36, 64L*2304, 128L*2304, 589824);
    CImg B = mkimg(b2, tPT, 24,24, 9, 64L*576, 128L*576, 147456);
    conv_mfma_d<<<dim3(45,2,4), 256, 0, stream>>>(A,B, wp+wpoff[2], nullptr, 64,128,32,2,
                                                  nullptr,nullptr,0,0);
    reduce_d<<<dim3(2304,2), 256, 0, stream>>>(tPR,tPT,Bp[2], rC,c2, 2, 589824,147456, 128, 2304,576, 128L*2304, 128L*576);
  }
  // L3 (S=2) + fused pool2 -> rE/e2
  {
    CImg A = mkimg(rC, tPR, 48,48, 36, 128L*2304, 128L*2304, 589824);
    CImg B = mkimg(c2, tPT, 24,24, 9, 128L*576, 128L*576, 147456);
    conv_mfma_d<<<dim3(45,2,4), 256, 0, stream>>>(A,B, wp+wpoff[3], nullptr, 128,128,64,2,
                                                  nullptr,nullptr,0,0);
    reduce_pool_d<<<dim3(576,2), 256, 0, stream>>>(tPR,tPT,Bp[3], rE,e2, 2, 589824,147456,
                                                   128, 48,48, 24,24);
  }
  // L4 (S=4)
  {
    CImg A = mkimg(rE, tPR, 24,24, 9, 128L*576, 256L*576, 294912);
    CImg B = mkimg(e2, tPT, 12,12, 4, 128L*144, 256L*144, 73728);
    conv_mfma_d<<<dim3(13,4,8), 256, 0, stream>>>(A,B, wp+wpoff[4], nullptr, 128,256,32,4,
                                                  nullptr,nullptr,0,0);
    reduce_d<<<dim3(1152,2), 256, 0, stream>>>(tPR,tPT,Bp[4], rF,f2, 4, 294912,73728, 256, 576,144, 256L*576, 256L*144);
  }
  // L5..L7 (S=4)
  const unsigned* inR[3] = {rF, rG, rF};  unsigned* outR[3] = {rG, rF, rG};
  const unsigned* inT[3] = {f2, g2, f2};  unsigned* outT[3] = {g2, f2, g2};
  for (int i=0;i<3;i++){
    int l = 5+i;
    CImg A = mkimg(inR[i], tPR, 24,24, 9, 256L*576, 256L*576, 294912);
    CImg B = mkimg(inT[i], tPT, 12,12, 4, 256L*144, 256L*144, 73728);
    conv_mfma_d<<<dim3(13,4,8), 256, 0, stream>>>(A,B, wp+wpoff[l], nullptr, 256,256,64,4,
                                                  nullptr,nullptr,0,0);
    reduce_d<<<dim3(1152,2), 256, 0, stream>>>(tPR,tPT,Bp[l], outR[i],outT[i], 4, 294912,73728, 256, 576,144, 256L*576, 256L*144);
  }
  // bicubic (packed in, fp32 out) + mean atomics for channels 64..319
  bicubic_d<<<dim3(256,4), 256, 0, stream>>>(rG, featR + 64L*9216, g2, featT + 64L*2304, meanb);

  // fused norm/split/transpose (mean already accumulated)
  split_bf16_d<<<dim3(360,2), 256, 0, stream>>>(featR, featT, meanb, AhR, AlR, BhT, BlT);

  // per-batch: GEMM(+colstat) -> merge -> conf/topk
  for (int b=0; b<2; b++){
    gemm_mfma<<<dim3(18,72), 256, 0, stream>>>(
        AhR + (long)b*9216*320, AlR + (long)b*9216*320,
        BhT + (long)b*2304*320, BlT + (long)b*2304*320, dist, cr, pm, ps);
    colstat_merge<<<dim3(9), 256, 0, stream>>>(pm, ps, qcol);
    conf_topk_f<<<dim3(9216), 256, 0, stream>>>(dist, cr, ct, qcol, (float*)d_out + (long)b*9216);
  }
}

// Round 16
// 451.811 us; speedup vs baseline: 1.0847x; 1.0847x over previous
//
#include <hip/hip_runtime.h>
#include <math.h>

#define CK_A (-0.75f)

typedef __attribute__((ext_vector_type(8))) short bf16x8;
typedef __attribute__((ext_vector_type(4))) float f32x4;

struct CImg { const void* in; void* out; int H, W, tiles; long inBS, outBS, sStride; };

__device__ __forceinline__ float cubicw(float t){
  float at = fabsf(t);
  float at2 = at*at, at3 = at2*at;
  if (at <= 1.f) return (CK_A+2.f)*at3 - (CK_A+3.f)*at2 + 1.f;
  if (at < 2.f)  return CK_A*at3 - 5.f*CK_A*at2 + 8.f*CK_A*at - 4.f*CK_A;
  return 0.f;
}

__device__ __forceinline__ unsigned short f2bf_rne(float f){
  unsigned int u = __float_as_uint(f);
  unsigned int r = (u + 0x7fffu + ((u>>16)&1u)) >> 16;
  return (unsigned short)r;
}
__device__ __forceinline__ float bf2f(unsigned short h){
  return __uint_as_float(((unsigned int)h)<<16);
}
__device__ __forceinline__ unsigned pack_bf(float v){
  unsigned short h = f2bf_rne(v);
  unsigned short l = f2bf_rne(v - bf2f(h));
  return ((unsigned)h<<16) | (unsigned)l;
}
__device__ __forceinline__ float unpack_bf(unsigned p){
  return bf2f((unsigned short)(p>>16)) + bf2f((unsigned short)(p&0xffffu));
}

__device__ __forceinline__ void merge_ms(float& m, float& s, float m2, float s2){
  float M = fmaxf(m, m2);
  s = s*__expf(m - M) + s2*__expf(m2 - M);
  m = M;
}

#define MFB(a,b,c) __builtin_amdgcn_mfma_f32_16x16x32_bf16(a,b,c,0,0,0)

typedef const __attribute__((address_space(1))) unsigned int* gp1_t;
typedef __attribute__((address_space(3))) unsigned int* lp3_t;
__device__ __forceinline__ void dma16(const void* g, void* l){
  __builtin_amdgcn_global_load_lds((gp1_t)g, (lp3_t)l, 16, 0, 0);
}

// ---------------- conv0: fp32 out to feat + packed aux for L1 -------------
__global__ __launch_bounds__(256) void conv0_d(CImg A, CImg B,
    const float* __restrict__ w, const float* __restrict__ bias,
    unsigned* __restrict__ pOutA, unsigned* __restrict__ pOutB){
  bool isA = (int)blockIdx.x < A.tiles;
  const float* in = (const float*)(isA ? A.in : B.in);
  float* out = (float*)(isA ? A.out : B.out);
  unsigned* pout = isA ? pOutA : pOutB;
  int H = isA ? A.H : B.H, W = isA ? A.W : B.W;
  long inBS = isA ? A.inBS : B.inBS, outBS = isA ? A.outBS : B.outBS;
  int tile = isA ? blockIdx.x : blockIdx.x - A.tiles;
  int tilesX = (W + 15) >> 4;
  int tx0 = (tile % tilesX) << 4, ty0 = (tile / tilesX) << 4;
  int cob = blockIdx.y * 4;
  int b = blockIdx.z;
  int lx = threadIdx.x & 15, ly = threadIdx.x >> 4;
  __shared__ float tile_s[3][18][20];
  float acc[4] = {0.f,0.f,0.f,0.f};
  const float* inb = in + (long)b*inBS;
  int ox = tx0+lx, oy = ty0+ly;
  int HW = H*W;

  for (int idx = threadIdx.x; idx < 3*324; idx += 256){
    int cl = idx/324, rem = idx - cl*324;
    int r = rem/18, c = rem - r*18;
    int gy = ty0 + r - 1, gx = tx0 + c - 1;
    const float* ic = inb + (long)cl*HW;
    tile_s[cl][r][c] = (gy>=0 && gy<H && gx>=0 && gx<W) ? ic[(long)gy*W+gx] : 0.f;
  }
  __syncthreads();
  #pragma unroll
  for (int cl=0; cl<3; cl++){
    float t00=tile_s[cl][ly+0][lx+0], t01=tile_s[cl][ly+0][lx+1], t02=tile_s[cl][ly+0][lx+2];
    float t10=tile_s[cl][ly+1][lx+0], t11=tile_s[cl][ly+1][lx+1], t12=tile_s[cl][ly+1][lx+2];
    float t20=tile_s[cl][ly+2][lx+0], t21=tile_s[cl][ly+2][lx+1], t22=tile_s[cl][ly+2][lx+2];
    #pragma unroll
    for (int j=0;j<4;j++){
      const float* wp = w + ((long)(cob+j)*3 + cl)*9;
      float a = acc[j];
      a = fmaf(t00, wp[0], a); a = fmaf(t01, wp[1], a); a = fmaf(t02, wp[2], a);
      a = fmaf(t10, wp[3], a); a = fmaf(t11, wp[4], a); a = fmaf(t12, wp[5], a);
      a = fmaf(t20, wp[6], a); a = fmaf(t21, wp[7], a); a = fmaf(t22, wp[8], a);
      acc[j] = a;
    }
  }
  if (ox < W && oy < H){
    #pragma unroll
    for (int j=0;j<4;j++){
      float v = fmaxf(acc[j] + bias[cob+j], 0.f);
      long pix = (long)(cob+j)*HW + (long)oy*W + ox;
      out[(long)b*outBS + pix] = v;
      pout[(long)b*64*HW + pix] = pack_bf(v);
    }
  }
}

// ---------------- weight pre-pack, all layers one launch ----------------
__global__ void prep_w_all(const float* __restrict__ w1, const float* __restrict__ w2,
                           const float* __restrict__ w3, const float* __restrict__ w4,
                           const float* __restrict__ w5, const float* __restrict__ w6,
                           const float* __restrict__ w7, unsigned short* __restrict__ wp){
  const int ciT[7] = {64,64,128,128,256,256,256};
  const int coT[7] = {64,128,128,256,256,256,256};
  int l = blockIdx.y;
  const float* w = l==0?w1: l==1?w2: l==2?w3: l==3?w4: l==4?w5: l==5?w6: w7;
  long offv = 0;
  for (int i=0;i<7;i++){ if (i<l) offv += 9L*ciT[i]*coT[i]*2; }
  long total = 9L*ciT[l]*coT[l]*2;
  long e = (long)blockIdx.x*256 + threadIdx.x;
  if (e >= total) return;
  int CI = ciT[l], CO = coT[l];
  int j = (int)(e & 7);
  int lane = (int)((e>>3) & 63);
  int h = (int)((e>>9) & 1);
  long rem = e >> 10;
  int G = CO >> 4, KC = CI >> 5;
  int g = (int)(rem % G); long q = rem / G;
  int kc = (int)(q % KC); int o = (int)(q / KC);
  int co = (g<<4) + (lane & 15);
  int ci = (kc<<5) + ((lane>>4)<<3) + j;
  float v = w[((long)co*CI + ci)*9 + o];
  unsigned short hi = f2bf_rne(v);
  wp[offv + e] = (h==0) ? hi : f2bf_rne(v - bf2f(hi));
}

// ---------------- implicit-GEMM MFMA conv, packed-u32 input --------------
union AB { bf16x8 v; uint4 u; };

__global__ __launch_bounds__(256) void conv_mfma_d(
    CImg A, CImg B, const unsigned short* __restrict__ Wp,
    const float* __restrict__ bias, int CI, int CO, int nci, int S)
{
  bool isA = (int)blockIdx.x < A.tiles;
  const unsigned* in = (const unsigned*)(isA ? A.in : B.in);
  void* outv = isA ? A.out : B.out;
  int H = isA ? A.H : B.H, W = isA ? A.W : B.W;
  long inBS = isA ? A.inBS : B.inBS, outBS = isA ? A.outBS : B.outBS;
  long sStride = isA ? A.sStride : B.sStride;
  int tile = isA ? blockIdx.x : blockIdx.x - A.tiles;

  int HW = H*W;
  int tilesX = (W+7)>>3;
  int tx0 = (tile % tilesX)<<3, ty0 = (tile / tilesX)<<3;
  int cobase = blockIdx.y << 6;
  int s = blockIdx.z % S, b = blockIdx.z / S;
  int tid = threadIdx.x, lane = tid & 63, wid = tid>>6;
  int wm = wid>>1, wn = wid&1;
  int KC = CI>>5, G = CO>>4;
  __shared__ __align__(16) unsigned short Bth[4000];
  __shared__ __align__(16) unsigned short Btl[4000];
  const unsigned* inb = in + (long)b*inBS;

  int sofs[13]; int sla[13];
  #pragma unroll
  for (int i=0;i<13;i++){
    int e = tid + i*256;
    int cidx = e / 100, pix = e - cidx*100;
    int hy = pix/10, hx = pix - hy*10;
    int gy = ty0 - 1 + hy, gx = tx0 - 1 + hx;
    bool v = (gy>=0) && (gy<H) && (gx>=0) && (gx<W);
    sofs[i] = v ? (cidx*HW + gy*W + gx) : -1;
    sla[i] = pix*40 + cidx;
  }

  int n15 = lane & 15;
  int klane8 = (lane>>4)<<3;
  int p0 = wn*32 + n15;
  int base0 = ((p0>>3)*10 + (p0&7))*40 + klane8;
  int p1 = p0 + 16;
  int base1 = ((p1>>3)*10 + (p1&7))*40 + klane8;
  int g0 = (cobase>>4) + wm*2;

  f32x4 acc[2][2];
  #pragma unroll
  for (int i=0;i<2;i++)
    #pragma unroll
    for (int j=0;j<2;j++) acc[i][j] = (f32x4){0.f,0.f,0.f,0.f};

  int nkc = nci >> 5;
  for (int kk=0; kk<nkc; kk++){
    int ci0 = s*nci + (kk<<5);
    __syncthreads();
    #pragma unroll
    for (int i=0;i<12;i++){
      unsigned p = (sofs[i] >= 0) ? inb[(long)ci0*HW + sofs[i]] : 0u;
      Bth[sla[i]] = (unsigned short)(p>>16);
      Btl[sla[i]] = (unsigned short)(p & 0xffffu);
    }
    if (tid < 128){
      unsigned p = (sofs[12] >= 0) ? inb[(long)ci0*HW + sofs[12]] : 0u;
      Bth[sla[12]] = (unsigned short)(p>>16);
      Btl[sla[12]] = (unsigned short)(p & 0xffffu);
    }
    __syncthreads();
    int kc = ci0 >> 5;
    const unsigned short* wpb = Wp + (long)kc*G*1024 + (long)lane*8;
    #pragma unroll
    for (int o=0;o<9;o++){
      const int dy = o/3, dx = o - dy*3;
      const int sh = (dy*10+dx)*40;
      const unsigned short* wo = wpb + (long)o*KC*G*1024;
      AB a0h,a0l,a1h,a1l, b0h,b0l,b1h,b1l;
      a0h.u = *(const uint4*)(wo + (long)g0*1024);
      a0l.u = *(const uint4*)(wo + (long)g0*1024 + 512);
      a1h.u = *(const uint4*)(wo + (long)(g0+1)*1024);
      a1l.u = *(const uint4*)(wo + (long)(g0+1)*1024 + 512);
      b0h.v = *(const bf16x8*)&Bth[base0 + sh];
      b0l.v = *(const bf16x8*)&Btl[base0 + sh];
      b1h.v = *(const bf16x8*)&Bth[base1 + sh];
      b1l.v = *(const bf16x8*)&Btl[base1 + sh];
      acc[0][0] = MFB(a0h.v, b0l.v, acc[0][0]);
      acc[0][0] = MFB(a0l.v, b0h.v, acc[0][0]);
      acc[0][0] = MFB(a0h.v, b0h.v, acc[0][0]);
      acc[0][1] = MFB(a0h.v, b1l.v, acc[0][1]);
      acc[0][1] = MFB(a0l.v, b1h.v, acc[0][1]);
      acc[0][1] = MFB(a0h.v, b1h.v, acc[0][1]);
      acc[1][0] = MFB(a1h.v, b0l.v, acc[1][0]);
      acc[1][0] = MFB(a1l.v, b0h.v, acc[1][0]);
      acc[1][0] = MFB(a1h.v, b0h.v, acc[1][0]);
      acc[1][1] = MFB(a1h.v, b1l.v, acc[1][1]);
      acc[1][1] = MFB(a1l.v, b1h.v, acc[1][1]);
      acc[1][1] = MFB(a1h.v, b1h.v, acc[1][1]);
    }
  }

  #pragma unroll
  for (int ng=0; ng<2; ng++){
    int p = wn*32 + ng*16 + n15;
    int gy = ty0 + (p>>3), gx = tx0 + (p&7);
    bool ok = (gy<H) && (gx<W);
    #pragma unroll
    for (int mg=0; mg<2; mg++){
      #pragma unroll
      for (int r=0;r<4;r++){
        if (ok){
          int co = cobase + wm*32 + mg*16 + ((lane>>4)<<2) + r;
          long idx = (long)co*HW + (long)gy*W + gx;
          float v = acc[mg][ng][r];
          if (bias){
            unsigned* outp = (unsigned*)outv + (long)b*outBS;
            outp[idx] = pack_bf(fmaxf(v + bias[co], 0.f));
          } else {
            float* outp = (float*)outv + (long)s*sStride + (long)b*outBS;
            outp[idx] = v;
          }
        }
      }
    }
  }
}

// ---------------- partial reduce + bias + relu -> packed out -------------
__global__ void reduce_d(const float* __restrict__ pA, const float* __restrict__ pB,
                         const float* __restrict__ bias,
                         unsigned* __restrict__ oA, unsigned* __restrict__ oB,
                         int S, long sStrA, long sStrB, int CO, int HWa, int HWb,
                         long oBSa, long oBSb){
  int img = blockIdx.y;
  const float* part = img ? pB : pA;
  unsigned* out = img ? oB : oA;
  int HW = img ? HWb : HWa;
  long sStride = img ? sStrB : sStrA;
  long outBS = img ? oBSb : oBSa;
  long tot = 2L*CO*HW;
  long e = (long)blockIdx.x*256 + threadIdx.x;
  if (e >= tot) return;
  long b = e / ((long)CO*HW);
  long r = e - b*(long)CO*HW;
  float v = 0.f;
  for (int s=0;s<S;s++) v += part[(long)s*sStride + e];
  int co = (int)(r / HW);
  out[b*outBS + r] = pack_bf(fmaxf(v + bias[co], 0.f));
}

// ---------------- maxpool 2x2 on packed values ----------------
__global__ void maxpool2_d(const unsigned* __restrict__ inA, unsigned* __restrict__ outA, long NCa, int HiA, int WiA,
                           const unsigned* __restrict__ inB, unsigned* __restrict__ outB, long NCb, int HiB, int WiB){
  const unsigned* in = blockIdx.y ? inB : inA;
  unsigned* out = blockIdx.y ? outB : outA;
  long NC = blockIdx.y ? NCb : NCa;
  int Hi = blockIdx.y ? HiB : HiA, Wi = blockIdx.y ? WiB : WiA;
  int Ho = Hi>>1, Wo = Wi>>1;
  long total = NC * Ho * Wo;
  long idx = (long)blockIdx.x*256 + threadIdx.x;
  if (idx >= total) return;
  int x = (int)(idx % Wo); long t = idx / Wo; int y = (int)(t % Ho); long nc = t / Ho;
  const unsigned* p = in + (nc*Hi + 2*y)*(long)Wi + 2*x;
  unsigned c0=p[0], c1=p[1], c2=p[Wi], c3=p[Wi+1];
  float v0=unpack_bf(c0), v1=unpack_bf(c1), v2=unpack_bf(c2), v3=unpack_bf(c3);
  unsigned best=c0; float bv=v0;
  if (v1>bv){bv=v1;best=c1;}
  if (v2>bv){bv=v2;best=c2;}
  if (v3>bv){bv=v3;best=c3;}
  out[idx] = best;
}

// ---------------- bicubic upsample from packed, fp32 out ----------------
__global__ __launch_bounds__(256) void bicubic_d(
    const unsigned* __restrict__ inA, float* __restrict__ outA,
    const unsigned* __restrict__ inB, float* __restrict__ outB){
  int c = blockIdx.x;
  int img = blockIdx.y >> 1, b = blockIdx.y & 1;
  const unsigned* in = img ? inB : inA;
  float* out = img ? outB : outA;
  int Hin = img ? 12 : 24, Win = Hin, Hout = img ? 48 : 96, Wout = Hout;
  long inBS = img ? 256L*144 : 256L*576;
  long outBS = img ? 320L*2304 : 320L*9216;
  __shared__ float s[576];
  const unsigned* ip = in + (long)b*inBS + (long)c*Hin*Win;
  float* op = out + (long)b*outBS + (long)c*Hout*Wout;
  int n = Hin*Win;
  for (int i = threadIdx.x; i < n; i += 256) s[i] = unpack_bf(ip[i]);
  __syncthreads();
  float scy = (float)((double)(Hin-1)/(double)(Hout-1));
  float scx = scy;
  int total = Hout*Wout;
  for (int idx = threadIdx.x; idx < total; idx += 256){
    int ox = idx % Wout, oy = idx / Wout;
    float py = oy * scy, px = ox * scx;
    float iy0f = floorf(py), ix0f = floorf(px);
    int iy0 = (int)iy0f, ix0 = (int)ix0f;
    float fy = py - iy0f, fx = px - ix0f;
    float wy[4], wx[4]; int xs[4], ys[4];
    #pragma unroll
    for (int t=0;t<4;t++){
      wy[t] = cubicw(fy - (float)(t-1));
      wx[t] = cubicw(fx - (float)(t-1));
      ys[t] = min(max(iy0 + t - 1, 0), Hin-1);
      xs[t] = min(max(ix0 + t - 1, 0), Win-1);
    }
    float acc = 0.f;
    #pragma unroll
    for (int i=0;i<4;i++){
      const float* row = &s[ys[i]*Win];
      float rs = wx[0]*row[xs[0]] + wx[1]*row[xs[1]] + wx[2]*row[xs[2]] + wx[3]*row[xs[3]];
      acc = fmaf(wy[i], rs, acc);
    }
    op[idx] = acc;
  }
}

// ---------------- channel mean ----------------
__global__ __launch_bounds__(256) void mean_k(const float* __restrict__ fR, const float* __restrict__ fT, float* __restrict__ mean){
  int c = blockIdx.x % 320, b = blockIdx.x / 320;
  const float* a = fR + ((long)b*320+c)*9216L;
  const float* t = fT + ((long)b*320+c)*2304L;
  float s = 0.f;
  for (int i=threadIdx.x;i<9216;i+=256) s += a[i];
  for (int i=threadIdx.x;i<2304;i+=256) s += t[i];
  __shared__ float sm[4];
  for (int o=32;o;o>>=1) s += __shfl_down(s,o);
  int lane = threadIdx.x & 63, wv = threadIdx.x >> 6;
  if (lane==0) sm[wv] = s;
  __syncthreads();
  if (threadIdx.x==0) mean[b*320+c] = (sm[0]+sm[1]+sm[2]+sm[3]) * (1.f/11520.f);
}

// ---------------- normalize + split + transpose (both feats) -------------
__global__ __launch_bounds__(256) void split_bf16_d(const float* __restrict__ fR, const float* __restrict__ fT,
    const float* __restrict__ mean,
    unsigned short* __restrict__ AhR, unsigned short* __restrict__ AlR,
    unsigned short* __restrict__ BhT, unsigned short* __restrict__ BlT){
  bool isR = blockIdx.x < 288;
  const float* feat = isR ? fR : fT;
  unsigned short* oh = isR ? AhR : BhT;
  unsigned short* ol = isR ? AlR : BlT;
  int P = isR ? 9216 : 2304;
  int m0 = (isR ? blockIdx.x : blockIdx.x - 288) * 32;
  int b = blockIdx.y;
  __shared__ unsigned int t[32][321];
  int ml = threadIdx.x & 31, kq = threadIdx.x >> 5;
  const float* fp = feat + (long)b*320*P + m0 + ml;
  for (int k = kq*40; k < kq*40+40; k++){
    float mu = mean[b*320+k];
    float v = (fp[(long)k*P] - mu) / (mu + 1e-8f);
    t[ml][k] = pack_bf(v);
  }
  __syncthreads();
  long base = ((long)b*P + m0)*320;
  for (int idx = threadIdx.x; idx < 32*320; idx += 256){
    int m = idx/320, k = idx - m*320;
    unsigned int p = t[m][k];
    oh[base + (long)m*320 + k] = (unsigned short)(p>>16);
    ol[base + (long)m*320 + k] = (unsigned short)(p & 0xffffu);
  }
}

// ---------------- split-bf16 MFMA dist GEMM + fused column stats --------
// XCD-chunked block swizzle (T1): 1296 blocks, 8 XCDs, 162 each -> every
// XCD owns 9 contiguous m-panels (A rows L2-resident per XCD).
// dist written with nontemporal stores (read-once stream, keep L2 for A/B).
__global__ __launch_bounds__(256) void gemm_mfma(
    const unsigned short* __restrict__ Ah, const unsigned short* __restrict__ Al,
    const unsigned short* __restrict__ Bh, const unsigned short* __restrict__ Bl,
    float* __restrict__ D, const float* __restrict__ coefr,
    float* __restrict__ pm, float* __restrict__ ps){
  const int N = 2304, K = 320;
  int flat = (int)blockIdx.y * 18 + (int)blockIdx.x;   // nwg = 1296, %8==0
  int nf = (flat & 7) * 162 + (flat >> 3);
  int mb = nf / 18, nb = nf - mb*18;
  int n0 = nb*128, m0 = mb*128;
  __shared__ __align__(16) unsigned short SF[16384];   // 32 KB
  int tid = threadIdx.x, lane = tid & 63, wid = tid >> 6;
  int wm = wid >> 1, wn = wid & 1;
  int n15 = lane & 15, q = lane >> 4;
  f32x4 acc[4][4];
  #pragma unroll
  for (int i=0;i<4;i++)
    #pragma unroll
    for (int j=0;j<4;j++) acc[i][j] = (f32x4){0.f,0.f,0.f,0.f};

  const unsigned short* srcB[8];
  #pragma unroll
  for (int i=0;i<8;i++){
    int li = i*256 + tid;
    int rem = li & 1023;
    int row = rem >> 3, sg = rem & 7;
    int seg = sg ^ (row & 7);
    if (li < 1024) srcB[i] = ((seg<4) ? Ah : Al) + (long)(m0+row)*K + (seg&3)*8;
    else           srcB[i] = ((seg<4) ? Bh : Bl) + (long)(n0+row)*K + (seg&3)*8;
  }

  int aH[4], aL[4], bH[4], bL[4];
  #pragma unroll
  for (int g=0; g<4; g++){
    int ra = wm*64 + g*16 + n15;
    int rb = wn*64 + g*16 + n15;
    aH[g] = ra*64 + (( q   ) ^ (ra&7))*8;
    aL[g] = ra*64 + ((q+4) ^ (ra&7))*8;
    bH[g] = 8192 + rb*64 + (( q   ) ^ (rb&7))*8;
    bL[g] = 8192 + rb*64 + ((q+4) ^ (rb&7))*8;
  }

  for (int k0=0; k0<K; k0+=32){
    __syncthreads();
    #pragma unroll
    for (int i=0;i<8;i++){
      dma16(srcB[i] + k0, (void*)&SF[((i<<8) + (wid<<6))<<3]);
    }
    __syncthreads();

    AB af[2][4], bf[2][4];
    #pragma unroll
    for (int g=0; g<4; g++){
      af[0][g].v = *(const bf16x8*)&SF[aH[g]];
      af[1][g].v = *(const bf16x8*)&SF[aL[g]];
      bf[0][g].v = *(const bf16x8*)&SF[bH[g]];
      bf[1][g].v = *(const bf16x8*)&SF[bL[g]];
    }
    #pragma unroll
    for (int mg=0; mg<4; mg++)
      #pragma unroll
      for (int ng=0; ng<4; ng++){
        acc[mg][ng] = MFB(af[0][mg].v, bf[1][ng].v, acc[mg][ng]);
        acc[mg][ng] = MFB(af[1][mg].v, bf[0][ng].v, acc[mg][ng]);
        acc[mg][ng] = MFB(af[0][mg].v, bf[0][ng].v, acc[mg][ng]);
      }
  }
  __syncthreads();

  #pragma unroll
  for (int mg=0; mg<4; mg++)
    #pragma unroll
    for (int ng=0; ng<4; ng++){
      int col = n0 + wn*64 + ng*16 + n15;
      #pragma unroll
      for (int r=0;r<4;r++){
        int rowv = m0 + wm*64 + mg*16 + q*4 + r;
        __builtin_nontemporal_store(acc[mg][ng][r], &D[(long)rowv*N + col]);
      }
    }

  float cr = *coefr;
  float* red = (float*)&SF[0];
  float pmv[4], psv[4];
  #pragma unroll
  for (int ng=0; ng<4; ng++){
    float m = -INFINITY;
    #pragma unroll
    for (int mg=0; mg<4; mg++)
      #pragma unroll
      for (int r=0;r<4;r++) m = fmaxf(m, cr*acc[mg][ng][r]);
    float s = 0.f;
    #pragma unroll
    for (int mg=0; mg<4; mg++)
      #pragma unroll
      for (int r=0;r<4;r++) s += __expf(cr*acc[mg][ng][r] - m);
    #pragma unroll
    for (int o=16;o<64;o<<=1){
      float m2 = __shfl_xor(m,o), s2 = __shfl_xor(s,o);
      merge_ms(m,s,m2,s2);
    }
    pmv[ng]=m; psv[ng]=s;
  }
  if (q==0){
    #pragma unroll
    for (int ng=0; ng<4; ng++){
      int cl = wn*64 + ng*16 + lane;
      red[wm*128 + cl] = pmv[ng];
      red[256 + wm*128 + cl] = psv[ng];
    }
  }
  __syncthreads();
  if (wm==0 && q==0){
    #pragma unroll
    for (int ng=0; ng<4; ng++){
      int cl = wn*64 + ng*16 + lane;
      float m = pmv[ng], s = psv[ng];
      merge_ms(m, s, red[128+cl], red[384+cl]);
      pm[(long)mb*2304 + n0 + cl] = m;
      ps[(long)mb*2304 + n0 + cl] = s;
    }
  }
}

// merge 72 partials, emit q[n] = 0.5*cmax + 0.5*log(csum)
__global__ void colstat_merge(const float* __restrict__ pm, const float* __restrict__ ps,
                              float* __restrict__ qcol){
  int idx = blockIdx.x*256 + threadIdx.x;
  if (idx >= 2304) return;
  float m=-INFINITY, s=0.f;
  for (int k=0;k<72;k++) merge_ms(m, s, pm[(long)k*2304+idx], ps[(long)k*2304+idx]);
  qcol[idx] = 0.5f*m + 0.5f*__logf(s);
}

// ---------------- fused row-stats + confidence + top-10 mean -------------
__global__ __launch_bounds__(256) void conf_topk_f(const float* __restrict__ D,
    const float* __restrict__ coefr, const float* __restrict__ coeft,
    const float* __restrict__ qcol, float* __restrict__ outp){
  int m = blockIdx.x;
  const float* drow = D + (long)m*2304;
  int tid = threadIdx.x, lane = tid & 63, wv = tid >> 6;
  float ct = *coeft, cr = *coefr;
  float v[9], tv[9];
  #pragma unroll
  for (int i=0;i<9;i++){ v[i] = __builtin_nontemporal_load(&drow[tid + i*256]); tv[i] = ct * v[i]; }

  __shared__ float sred[8];
  __shared__ unsigned int cand[40];

  float mx = tv[0];
  #pragma unroll
  for (int i=1;i<9;i++) mx = fmaxf(mx, tv[i]);
  #pragma unroll
  for (int o=1;o<64;o<<=1) mx = fmaxf(mx, __shfl_xor(mx, o));
  if (lane==0) sred[wv] = mx;
  __syncthreads();
  mx = fmaxf(fmaxf(sred[0],sred[1]), fmaxf(sred[2],sred[3]));
  float s = 0.f;
  #pragma unroll
  for (int i=0;i<9;i++) s += __expf(tv[i]-mx);
  #pragma unroll
  for (int o=1;o<64;o<<=1) s += __shfl_xor(s, o);
  if (lane==0) sred[4+wv] = s;
  __syncthreads();
  float rs = sred[4]+sred[5]+sred[6]+sred[7];
  float rho = 0.5f*mx + 0.5f*__logf(rs);
  float hc = 0.5f*(cr+ct);

  unsigned int key[9];
  #pragma unroll
  for (int i=0;i<9;i++){
    int n = i*256 + tid;
    float t = fmaf(hc, v[i], -qcol[n]);
    unsigned int b = __float_as_uint(t);
    b ^= (b >> 31) ? 0xFFFFFFFFu : 0x80000000u;
    key[i] = (b & 0xFFFFF000u) | (unsigned)n;
  }

  for (int t10=0; t10<10; t10++){
    unsigned int lb = key[0];
    #pragma unroll
    for (int i=1;i<9;i++) lb = lb > key[i] ? lb : key[i];
    unsigned int wb = lb;
    #pragma unroll
    for (int o=1;o<64;o<<=1){
      unsigned int x = (unsigned int)__shfl_xor((int)wb, o);
      wb = wb > x ? wb : x;
    }
    if (lane==0) cand[wv*10 + t10] = wb;
    #pragma unroll
    for (int i=0;i<9;i++) if (key[i]==wb) key[i]=0;
  }
  __syncthreads();

  if (wv == 0){
    unsigned int k = (lane < 40) ? cand[lane] : 0u;
    int sel = -1;
    for (int t10=0; t10<10; t10++){
      unsigned int wb = k;
      #pragma unroll
      for (int o=1;o<64;o<<=1){
        unsigned int x = (unsigned int)__shfl_xor((int)wb, o);
        wb = wb > x ? wb : x;
      }
      if (k == wb) k = 0;
      if (lane == t10) sel = (int)(wb & 0xFFFu);
    }
    float c = 0.f;
    if (sel >= 0){
      float t = fmaf(hc, drow[sel], -qcol[sel]);
      c = __expf(t - rho);
    }
    #pragma unroll
    for (int o=1;o<64;o<<=1) c += __shfl_xor(c, o);
    if (lane == 0) outp[m] = c * 0.1f;
  }
}

// ---------------- host ----------------
extern "C" void kernel_launch(void* const* d_in, const int* in_sizes, int n_in,
                              void* d_out, int out_size, void* d_ws, size_t ws_size,
                              hipStream_t stream) {
  const float *W[8], *Bp[8], *xr, *xt, *cr, *ct;
  if (in_sizes[0] == 1728){
    for (int i=0;i<8;i++){ W[i]=(const float*)d_in[2*i]; Bp[i]=(const float*)d_in[2*i+1]; }
    xr=(const float*)d_in[16]; xt=(const float*)d_in[17];
    cr=(const float*)d_in[18]; ct=(const float*)d_in[19];
  } else {
    xr=(const float*)d_in[0]; xt=(const float*)d_in[1];
    cr=(const float*)d_in[2]; ct=(const float*)d_in[3];
    for (int i=0;i<8;i++){ W[i]=(const float*)d_in[4+2*i]; Bp[i]=(const float*)d_in[5+2*i]; }
  }

  const int convCI[8] = {3,64,64,128,128,256,256,256};
  const int convCO[8] = {64,64,128,128,256,256,256,256};
  long wpoff[8]; long wtot = 0;
  for (int l=1;l<8;l++){ wpoff[l] = wtot; wtot += 9L*convCI[l]*convCO[l]*2; }

  float* ws = (float*)d_ws;
  long off = 0;
  auto alloc = [&](long nfl){ float* p = ws + off; off += (nfl + 63) & ~63L; return p; };
  float* featR = alloc(2L*320*9216);
  float* featT = alloc(2L*320*2304);
  float* meanb = alloc(640);
  float* pm    = alloc(72L*2304);
  float* ps    = alloc(72L*2304);
  float* qcol  = alloc(2304);
  unsigned short* wp = (unsigned short*)alloc((wtot+1)/2);
  float* scratch = alloc(9216L*2304);
  if ((size_t)(off*4) > ws_size) return;

  unsigned short* AhR = (unsigned short*)alloc((2L*9216*320 + 1)/2);
  unsigned short* AlR = (unsigned short*)alloc((2L*9216*320 + 1)/2);
  unsigned short* BhT = (unsigned short*)alloc((2L*2304*320 + 1)/2);
  unsigned short* BlT = (unsigned short*)alloc((2L*2304*320 + 1)/2);
  if ((size_t)(off*4) > ws_size) return;

  // conv temporaries (packed u32 feature maps) inside the dist region
  unsigned* pc0R = (unsigned*)scratch;        // [2,64,96,96] conv0 packed
  unsigned* pc0T = pc0R + 1179648;            // [2,64,48,48]
  unsigned* rA   = pc0T + 294912;             // [2,64,96,96] L1 R out
  unsigned* rB   = rA + 1179648;              // [2,64,48,48] pool1 R
  unsigned* rC   = rB + 294912;               // [2,128,48,48]
  unsigned* rD   = rC + 589824;               // [2,128,48,48]
  unsigned* rE   = rD + 589824;               // [2,128,24,24]
  unsigned* rF   = rE + 147456;               // [2,256,24,24]
  unsigned* rG   = rF + 294912;               // [2,256,24,24]
  unsigned* a2   = rG + 294912;               // [2,64,48,48]
  unsigned* b2   = a2 + 294912;               // [2,64,24,24]
  unsigned* c2   = b2 + 73728;                // [2,128,24,24]
  unsigned* d2   = c2 + 147456;               // [2,128,24,24]
  unsigned* e2   = d2 + 147456;               // [2,128,12,12]
  unsigned* f2   = e2 + 36864;                // [2,256,12,12]
  unsigned* g2   = f2 + 73728;                // [2,256,12,12]
  float* tPR = (float*)(g2 + 73728);          // R partials fp32
  float* tPT = tPR + 1179648;                 // T partials fp32
  float* dist = scratch;

  auto mkimg = [](const void* in, void* out, int H, int Wd, int tiles,
                  long inBS, long outBS, long sStr){
    CImg c; c.in=in; c.out=out; c.H=H; c.W=Wd; c.tiles=tiles;
    c.inBS=inBS; c.outBS=outBS; c.sStride=sStr; return c;
  };

  prep_w_all<<<dim3(4608,7), 256, 0, stream>>>(W[1],W[2],W[3],W[4],W[5],W[6],W[7], wp);

  // conv0 (both images): fp32 into feat + packed aux
  {
    CImg A = mkimg(xr, featR, 96,96, 36, 3L*9216, 320L*9216, 0);
    CImg B = mkimg(xt, featT, 48,48, 9, 3L*2304, 320L*2304, 0);
    conv0_d<<<dim3(45,16,2), 256, 0, stream>>>(A, B, W[0], Bp[0], pc0R, pc0T);
  }
  // L1 (S=1, packed in/out)
  {
    CImg A = mkimg(pc0R, rA, 96,96, 144, 64L*9216, 64L*9216, 0);
    CImg B = mkimg(pc0T, a2, 48,48, 36, 64L*2304, 64L*2304, 0);
    conv_mfma_d<<<dim3(180,1,2), 256, 0, stream>>>(A,B, wp+wpoff[1], Bp[1], 64,64,64,1);
  }
  maxpool2_d<<<dim3(1152,2), 256, 0, stream>>>(rA,rB,128,96,96, a2,b2,128,48,48);
  // L2 (S=2)
  {
    CImg A = mkimg(rB, tPR, 48,48, 36, 64L*2304, 128L*2304, 589824);
    CImg B = mkimg(b2, tPT, 24,24, 9, 64L*576, 128L*576, 147456);
    conv_mfma_d<<<dim3(45,2,4), 256, 0, stream>>>(A,B, wp+wpoff[2], nullptr, 64,128,32,2);
    reduce_d<<<dim3(2304,2), 256, 0, stream>>>(tPR,tPT,Bp[2], rC,c2, 2, 589824,147456, 128, 2304,576, 128L*2304, 128L*576);
  }
  // L3 (S=2)
  {
    CImg A = mkimg(rC, tPR, 48,48, 36, 128L*2304, 128L*2304, 589824);
    CImg B = mkimg(c2, tPT, 24,24, 9, 128L*576, 128L*576, 147456);
    conv_mfma_d<<<dim3(45,2,4), 256, 0, stream>>>(A,B, wp+wpoff[3], nullptr, 128,128,64,2);
    reduce_d<<<dim3(2304,2), 256, 0, stream>>>(tPR,tPT,Bp[3], rD,d2, 2, 589824,147456, 128, 2304,576, 128L*2304, 128L*576);
  }
  maxpool2_d<<<dim3(576,2), 256, 0, stream>>>(rD,rE,256,48,48, d2,e2,256,24,24);
  // L4 (S=4)
  {
    CImg A = mkimg(rE, tPR, 24,24, 9, 128L*576, 256L*576, 294912);
    CImg B = mkimg(e2, tPT, 12,12, 4, 128L*144, 256L*144, 73728);
    conv_mfma_d<<<dim3(13,4,8), 256, 0, stream>>>(A,B, wp+wpoff[4], nullptr, 128,256,32,4);
    reduce_d<<<dim3(1152,2), 256, 0, stream>>>(tPR,tPT,Bp[4], rF,f2, 4, 294912,73728, 256, 576,144, 256L*576, 256L*144);
  }
  // L5..L7 (S=4)
  const unsigned* inR[3] = {rF, rG, rF};  unsigned* outR[3] = {rG, rF, rG};
  const unsigned* inT[3] = {f2, g2, f2};  unsigned* outT[3] = {g2, f2, g2};
  for (int i=0;i<3;i++){
    int l = 5+i;
    CImg A = mkimg(inR[i], tPR, 24,24, 9, 256L*576, 256L*576, 294912);
    CImg B = mkimg(inT[i], tPT, 12,12, 4, 256L*144, 256L*144, 73728);
    conv_mfma_d<<<dim3(13,4,8), 256, 0, stream>>>(A,B, wp+wpoff[l], nullptr, 256,256,64,4);
    reduce_d<<<dim3(1152,2), 256, 0, stream>>>(tPR,tPT,Bp[l], outR[i],outT[i], 4, 294912,73728, 256, 576,144, 256L*576, 256L*144);
  }
  // bicubic (packed in, fp32 out)
  bicubic_d<<<dim3(256,4), 256, 0, stream>>>(rG, featR + 64L*9216, g2, featT + 64L*2304);

  // normalizer mean + fused norm/split/transpose (one launch)
  mean_k<<<640, 256, 0, stream>>>(featR, featT, meanb);
  split_bf16_d<<<dim3(360,2), 256, 0, stream>>>(featR, featT, meanb, AhR, AlR, BhT, BlT);

  // per-batch: GEMM(+colstat) -> merge -> conf/topk
  for (int b=0; b<2; b++){
    gemm_mfma<<<dim3(18,72), 256, 0, stream>>>(
        AhR + (long)b*9216*320, AlR + (long)b*9216*320,
        BhT + (long)b*2304*320, BlT + (long)b*2304*320, dist, cr, pm, ps);
    colstat_merge<<<dim3(9), 256, 0, stream>>>(pm, ps, qcol);
    conf_topk_f<<<dim3(9216), 256, 0, stream>>>(dist, cr, ct, qcol, (float*)d_out + (long)b*9216);
  }
}